// Round 1
// baseline (375.526 us; speedup 1.0000x reference)
//
#include <hip/hip_runtime.h>
#include <hip/hip_fp16.h>

#define H_   256
#define W_   256
#define HW_  65536
#define NIMG 8

#define TI   32
#define TJ   32
#define HALO 10
#define RD   52   // TI + 2*HALO

__device__ __forceinline__ __half2 u2h(unsigned int u) {
    union { unsigned int u; __half2 h; } v; v.u = u; return v.h;
}
__device__ __forceinline__ unsigned int h2u(__half2 h) {
    union { unsigned int u; __half2 h; } v; v.h = h; return v.u;
}

// ---------------- Kernel A: pointwise conv (fp32) + offset scalar ----------------
// y stored as packed f16 channel-pairs: ypack[(n*32 + p)*HW + hw] = (y[2p], y[2p+1])
__global__ __launch_bounds__(256) void pw_off_kernel(
    const float* __restrict__ x, const float* __restrict__ pw,
    const float* __restrict__ offw, const float* __restrict__ offb,
    unsigned int* __restrict__ ypack, float* __restrict__ sbuf)
{
    __shared__ float wT[64 * 64];   // wT[c*64+o] = pw[o*64+c]
    __shared__ float ow[64];
    const int t = threadIdx.x;
    for (int i = t; i < 4096; i += 256) {
        int o = i >> 6, c = i & 63;
        wT[c * 64 + o] = pw[i];
    }
    if (t < 64) ow[t] = offw[t];
    __syncthreads();

    const int b   = blockIdx.x;          // 1024 blocks, 512 px each
    const int n   = b >> 7;              // 128 blocks per image
    const int hw0 = (b & 127) << 9;
    const size_t xbase = (size_t)n * 64 * HW_ + hw0 + t;

    float acc0[64], acc1[64];
    #pragma unroll
    for (int o = 0; o < 64; ++o) { acc0[o] = 0.f; acc1[o] = 0.f; }

    for (int c = 0; c < 64; ++c) {
        float xv0 = x[xbase + (size_t)c * HW_];
        float xv1 = x[xbase + (size_t)c * HW_ + 256];
        const float4* w4 = (const float4*)&wT[c * 64];
        #pragma unroll
        for (int o4 = 0; o4 < 16; ++o4) {
            float4 w = w4[o4];
            acc0[4*o4+0] += w.x * xv0;  acc1[4*o4+0] += w.x * xv1;
            acc0[4*o4+1] += w.y * xv0;  acc1[4*o4+1] += w.y * xv1;
            acc0[4*o4+2] += w.z * xv0;  acc1[4*o4+2] += w.z * xv1;
            acc0[4*o4+3] += w.w * xv0;  acc1[4*o4+3] += w.w * xv1;
        }
    }

    float s0 = 0.f, s1 = 0.f;
    #pragma unroll
    for (int o = 0; o < 64; ++o) { s0 += acc0[o] * ow[o]; s1 += acc1[o] * ow[o]; }
    float bias = offb[0];
    s0 = fminf(fmaxf(s0 + bias, 0.f), 8.f);
    s1 = fminf(fmaxf(s1 + bias, 0.f), 8.f);
    sbuf[n * HW_ + hw0 + t]       = s0;
    sbuf[n * HW_ + hw0 + 256 + t] = s1;

    const size_t ybase = (size_t)n * 32 * HW_ + hw0 + t;
    #pragma unroll
    for (int p = 0; p < 32; ++p) {
        ypack[ybase + (size_t)p * HW_]       = h2u(__floats2half2_rn(acc0[2*p], acc0[2*p+1]));
        ypack[ybase + (size_t)p * HW_ + 256] = h2u(__floats2half2_rn(acc1[2*p], acc1[2*p+1]));
    }
}

// ---------------- Kernel B: deformable depthwise 3x3, separable bilinear ----------------
// block = 32x32 pixel tile x 4 channel-pairs (8 channels). Stage 52x52 zero-padded
// region per pair-plane into LDS, interpolate in packed f16.
__global__ __launch_bounds__(256) void deform_kernel(
    const unsigned int* __restrict__ ypack, const float* __restrict__ sbuf,
    const float* __restrict__ dwp, float* __restrict__ out)
{
    __shared__ unsigned int smem[4][RD * RD];
    __shared__ unsigned int dw2s[4][9];

    const int t  = threadIdx.x;
    const int tj = blockIdx.x;   // 0..7
    const int ti = blockIdx.y;   // 0..7
    const int z  = blockIdx.z;   // n*8 + pb
    const int n  = z >> 3;
    const int pb = z & 7;
    const int i0 = ti * TI, j0 = tj * TJ;

    if (t < 36) {
        int ppl = t / 9, k = t - ppl * 9;
        int c0 = (pb * 4 + ppl) * 2;
        dw2s[ppl][k] = h2u(__floats2half2_rn(dwp[c0 * 9 + k], dwp[(c0 + 1) * 9 + k]));
    }

    // stage zero-padded region for 4 pair-planes
    const size_t ybase = ((size_t)n * 32 + pb * 4) * HW_;
    for (int idx = t; idx < RD * RD; idx += 256) {
        int r  = idx / RD;
        int c  = idx - r * RD;
        int gr = i0 - HALO + r;
        int gc = j0 - HALO + c;
        bool ok = (gr >= 0) && (gr < H_) && (gc >= 0) && (gc < W_);
        int off = gr * W_ + gc;
        #pragma unroll
        for (int ppl = 0; ppl < 4; ++ppl)
            smem[ppl][idx] = ok ? ypack[ybase + (size_t)ppl * HW_ + off] : 0u;
    }
    __syncthreads();

    // per-pixel geometry (4 pixels per thread), shared across channel planes
    int rowO[4][5]; int colO[4][5];
    unsigned int fwr[4][4];   // fya2, fyb2, fxa2, fxb2 (half2-broadcast)
    #pragma unroll
    for (int q = 0; q < 4; ++q) {
        int li = (t >> 5) + q * 8;
        int lj = (t & 31);
        int gi = i0 + li, gj = j0 + lj;
        float sv = sbuf[n * HW_ + gi * W_ + gj];
        float tt = 1.0f + sv;
        float lr = (float)(li + HALO);
        float lc = (float)(lj + HALO);
        float pa = lr - tt, pbr = lr + tt;
        float qa = lc - tt, qbr = lc + tt;
        int ra0 = (int)floorf(pa);  float fya = pa - (float)ra0;
        int rb0 = (int)floorf(pbr); float fyb = pbr - (float)rb0;
        int ca0 = (int)floorf(qa);  float fxa = qa - (float)ca0;
        int cb0 = (int)floorf(qbr); float fxb = qbr - (float)cb0;
        rowO[q][0] = ra0 * RD; rowO[q][1] = rowO[q][0] + RD;
        rowO[q][2] = (li + HALO) * RD;
        rowO[q][3] = rb0 * RD; rowO[q][4] = rowO[q][3] + RD;
        colO[q][0] = ca0; colO[q][1] = ca0 + 1;
        colO[q][2] = lj + HALO;
        colO[q][3] = cb0; colO[q][4] = cb0 + 1;
        fwr[q][0] = h2u(__half2half2(__float2half_rn(fya)));
        fwr[q][1] = h2u(__half2half2(__float2half_rn(fyb)));
        fwr[q][2] = h2u(__half2half2(__float2half_rn(fxa)));
        fwr[q][3] = h2u(__half2half2(__float2half_rn(fxb)));
    }

    #pragma unroll
    for (int ppl = 0; ppl < 4; ++ppl) {
        __half2 d[9];
        #pragma unroll
        for (int k = 0; k < 9; ++k) d[k] = u2h(dw2s[ppl][k]);
        const unsigned int* L = smem[ppl];
        #pragma unroll
        for (int q = 0; q < 4; ++q) {
            __half2 fya2 = u2h(fwr[q][0]), fyb2 = u2h(fwr[q][1]);
            __half2 fxa2 = u2h(fwr[q][2]), fxb2 = u2h(fwr[q][3]);
            __half2 colA[5], colC[5], colB[5];
            #pragma unroll
            for (int r = 0; r < 5; ++r) {
                const unsigned int* Lr = L + rowO[q][r];
                __half2 v0 = u2h(Lr[colO[q][0]]);
                __half2 v1 = u2h(Lr[colO[q][1]]);
                __half2 v2 = u2h(Lr[colO[q][2]]);
                __half2 v3 = u2h(Lr[colO[q][3]]);
                __half2 v4 = u2h(Lr[colO[q][4]]);
                colA[r] = __hfma2(fxa2, __hsub2(v1, v0), v0);
                colC[r] = v2;
                colB[r] = __hfma2(fxb2, __hsub2(v4, v3), v3);
            }
            __half2 acc = u2h(0u);
            // kx = 0 : column a
            {
                __half2 SA = __hfma2(fya2, __hsub2(colA[1], colA[0]), colA[0]);
                __half2 SB = __hfma2(fyb2, __hsub2(colA[4], colA[3]), colA[3]);
                acc = __hfma2(d[0], SA, acc);
                acc = __hfma2(d[3], colA[2], acc);
                acc = __hfma2(d[6], SB, acc);
            }
            // kx = 1 : center column
            {
                __half2 SA = __hfma2(fya2, __hsub2(colC[1], colC[0]), colC[0]);
                __half2 SB = __hfma2(fyb2, __hsub2(colC[4], colC[3]), colC[3]);
                acc = __hfma2(d[1], SA, acc);
                acc = __hfma2(d[4], colC[2], acc);
                acc = __hfma2(d[7], SB, acc);
            }
            // kx = 2 : column b
            {
                __half2 SA = __hfma2(fya2, __hsub2(colB[1], colB[0]), colB[0]);
                __half2 SB = __hfma2(fyb2, __hsub2(colB[4], colB[3]), colB[3]);
                acc = __hfma2(d[2], SA, acc);
                acc = __hfma2(d[5], colB[2], acc);
                acc = __hfma2(d[8], SB, acc);
            }
            int li = (t >> 5) + q * 8, lj = t & 31;
            int gi = i0 + li, gj = j0 + lj;
            int c0 = (pb * 4 + ppl) * 2;
            size_t ob = ((size_t)n * 64 + c0) * HW_ + gi * W_ + gj;
            out[ob]       = __low2float(acc);
            out[ob + HW_] = __high2float(acc);
        }
    }
}

extern "C" void kernel_launch(void* const* d_in, const int* in_sizes, int n_in,
                              void* d_out, int out_size, void* d_ws, size_t ws_size,
                              hipStream_t stream) {
    const float* x    = (const float*)d_in[0];
    const float* pw   = (const float*)d_in[1];
    const float* offw = (const float*)d_in[2];
    const float* offb = (const float*)d_in[3];
    const float* dwp  = (const float*)d_in[4];

    unsigned int* ypack = (unsigned int*)d_ws;                       // 8*32*HW u32 = 64 MiB
    float* sbuf = (float*)((char*)d_ws + (size_t)NIMG * 32 * HW_ * 4); // 2 MiB
    float* out  = (float*)d_out;

    hipLaunchKernelGGL(pw_off_kernel, dim3(1024), dim3(256), 0, stream,
                       x, pw, offw, offb, ypack, sbuf);
    hipLaunchKernelGGL(deform_kernel, dim3(8, 8, NIMG * 8), dim3(256), 0, stream,
                       ypack, sbuf, dwp, out);
}

// Round 3
// 296.751 us; speedup vs baseline: 1.2655x; 1.2655x over previous
//
#include <hip/hip_runtime.h>
#include <hip/hip_fp16.h>
#include <stdint.h>

#define H_   256
#define W_   256
#define HW_  65536
#define NIMG 8

#define TI   32
#define TJ   32
#define HALO 10
#define RD   52   // TI + 2*HALO

typedef _Float16 half8_t __attribute__((ext_vector_type(8)));
typedef __fp16   fp16x2  __attribute__((ext_vector_type(2)));
typedef float    float4_t __attribute__((ext_vector_type(4)));

__device__ __forceinline__ uint32_t pk2(float a, float b) {
    fp16x2 h = __builtin_amdgcn_cvt_pkrtz(a, b);
    union { fp16x2 h; uint32_t u; } v; v.h = h; return v.u;
}
__device__ __forceinline__ __half2 u2h(uint32_t u) {
    union { uint32_t u; __half2 h; } v; v.u = u; return v.h;
}
__device__ __forceinline__ __half2 lerp2(__half2 p, __half2 q, __half2 f) {
    return __hfma2(f, __hsub2(q, p), p);
}

// ---------------- Kernel A: pointwise conv via MFMA f16 + offset scalar ----------------
// ypackI layout (u32): [(n*8 + pg)*HW + hw]*4 + ppl, pg in [0,8), ppl in [0,4)
// channel c = pg*8 + ppl*2 (+1 in high half of the half2)
__global__ __launch_bounds__(256) void pw_off_kernel(
    const float* __restrict__ x, const float* __restrict__ pw,
    const float* __restrict__ offw, const float* __restrict__ offb,
    uint32_t* __restrict__ ypackI, float* __restrict__ sbuf)
{
    // Xs rows = channel-pairs c2 (32), cols = pixels (256 half2) padded to 260 dwords
    __shared__ uint32_t Xs[32 * 260];
    const int t    = threadIdx.x;
    const int blk  = blockIdx.x;          // 2048 blocks, 256 px each
    const int n    = blk >> 8;
    const int hw0  = (blk & 255) << 8;
    const int lane = t & 63;
    const int l15  = lane & 15;
    const int q    = lane >> 4;

    // ---- stage x (fp32) -> f16 pairs in LDS, pixel-major per c2 row ----
    {
        const int pq  = t & 63;           // pixel quad
        const int c2b = (t >> 6) * 8;
        const float* xb = x + (size_t)n * 64 * HW_ + hw0 + pq * 4;
        #pragma unroll
        for (int i = 0; i < 8; ++i) {
            int c2 = c2b + i;
            float4 a = *(const float4*)(xb + (size_t)(2 * c2) * HW_);
            float4 b = *(const float4*)(xb + (size_t)(2 * c2 + 1) * HW_);
            uint4 w;
            w.x = pk2(a.x, b.x); w.y = pk2(a.y, b.y);
            w.z = pk2(a.z, b.z); w.w = pk2(a.w, b.w);
            *(uint4*)&Xs[c2 * 260 + pq * 4] = w;
        }
    }

    // ---- A fragments: af[mt][kt], A[m][k]: m = l15, k = q*8 + j ----
    half8_t af[4][2];
    #pragma unroll
    for (int mt = 0; mt < 4; ++mt) {
        #pragma unroll
        for (int kt = 0; kt < 2; ++kt) {
            const float* wr = pw + (mt * 16 + l15) * 64 + kt * 32 + q * 8;
            float4 w0 = *(const float4*)wr;
            float4 w1 = *(const float4*)(wr + 4);
            union { uint32_t u[4]; half8_t h; } v;
            v.u[0] = pk2(w0.x, w0.y); v.u[1] = pk2(w0.z, w0.w);
            v.u[2] = pk2(w1.x, w1.y); v.u[3] = pk2(w1.z, w1.w);
            af[mt][kt] = v.h;
        }
    }
    float4_t ow4[4];
    #pragma unroll
    for (int mt = 0; mt < 4; ++mt)
        ow4[mt] = *(const float4_t*)(offw + mt * 16 + q * 4);
    const float bias = offb[0];
    __syncthreads();

    const int wv = t >> 6;
    #pragma unroll
    for (int j = 0; j < 4; ++j) {
        const int nt  = wv * 4 + j;
        const int pix = nt * 16 + l15;
        const int hw  = hw0 + pix;
        // B fragments: B[k][nn]: nn = l15 (pixel), k = q*8 + jj
        half8_t bf[2];
        #pragma unroll
        for (int kt = 0; kt < 2; ++kt) {
            union { uint32_t u[4]; half8_t h; } v;
            const int rbase = kt * 16 + q * 4;
            v.u[0] = Xs[(rbase + 0) * 260 + pix];
            v.u[1] = Xs[(rbase + 1) * 260 + pix];
            v.u[2] = Xs[(rbase + 2) * 260 + pix];
            v.u[3] = Xs[(rbase + 3) * 260 + pix];
            bf[kt] = v.h;
        }
        float4_t acc[4] = {{0,0,0,0},{0,0,0,0},{0,0,0,0},{0,0,0,0}};
        #pragma unroll
        for (int kt = 0; kt < 2; ++kt) {
            #pragma unroll
            for (int mt = 0; mt < 4; ++mt)
                acc[mt] = __builtin_amdgcn_mfma_f32_16x16x32_f16(af[mt][kt], bf[kt], acc[mt], 0, 0, 0);
        }

        // ---- offset scalar: s = clip(y . ow + b) — reduce over the 4 quads ----
        float sp = 0.f;
        #pragma unroll
        for (int mt = 0; mt < 4; ++mt)
            sp += acc[mt][0] * ow4[mt][0] + acc[mt][1] * ow4[mt][1]
                + acc[mt][2] * ow4[mt][2] + acc[mt][3] * ow4[mt][3];
        sp += __shfl_xor(sp, 16, 64);
        sp += __shfl_xor(sp, 32, 64);
        float sv = fminf(fmaxf(sp + bias, 0.f), 8.f);
        if (q == 0) sbuf[(size_t)n * HW_ + hw] = sv;

        // ---- pack y to f16 pairs, store interleaved-by-4-planes ----
        #pragma unroll
        for (int mt = 0; mt < 4; ++mt) {
            uint2 st;
            st.x = pk2(acc[mt][0], acc[mt][1]);
            st.y = pk2(acc[mt][2], acc[mt][3]);
            const int pg = mt * 2 + (q >> 1);
            size_t ad = (((size_t)(n * 8 + pg)) * HW_ + hw) * 4 + (q & 1) * 2;
            *(uint2*)&ypackI[ad] = st;
        }
    }
}

// ---------------- Kernel B: deformable depthwise 3x3, separable bilinear ----------------
// block = 32x32 pixel tile x 1 plane-group (4 half2-planes = 8 channels).
// Staged region interleaved: one ds_read_b128 per sample point serves 8 channels.
__global__ __launch_bounds__(256) void deform_kernel(
    const uint4* __restrict__ ypackI, const float* __restrict__ sbuf,
    const float* __restrict__ dwp, float* __restrict__ out)
{
    __shared__ uint4 smem[RD * RD];   // 43.3 KB

    const int t  = threadIdx.x;
    const int tj = blockIdx.x;   // 0..7
    const int ti = blockIdx.y;   // 0..7
    const int z  = blockIdx.z;   // n*8 + pg
    const int n  = z >> 3;
    const int pg = z & 7;
    const int i0 = ti * TI, j0 = tj * TJ;

    // stage zero-padded interleaved region
    const size_t ybase = (size_t)z * HW_;
    for (int idx = t; idx < RD * RD; idx += 256) {
        int r  = idx / RD;
        int c  = idx - r * RD;
        int gr = i0 - HALO + r;
        int gc = j0 - HALO + c;
        bool ok = (gr >= 0) & (gr < H_) & (gc >= 0) & (gc < W_);
        uint4 v = {0u, 0u, 0u, 0u};
        if (ok) v = ypackI[ybase + gr * W_ + gc];
        smem[idx] = v;
    }

    // depthwise weights (uniform scalar loads), packed per channel-pair
    const int c0 = pg * 8;
    __half2 d2[4][9];
    #pragma unroll
    for (int pp = 0; pp < 4; ++pp) {
        #pragma unroll
        for (int k = 0; k < 9; ++k)
            d2[pp][k] = __floats2half2_rn(dwp[(c0 + 2 * pp) * 9 + k],
                                          dwp[(c0 + 2 * pp + 1) * 9 + k]);
    }
    __syncthreads();

    #pragma unroll
    for (int qq = 0; qq < 4; ++qq) {
        const int li = (t >> 5) + qq * 8;
        const int lj = t & 31;
        const int gi = i0 + li, gj = j0 + lj;
        const float sv = sbuf[(size_t)n * HW_ + gi * W_ + gj];
        const float tt = 1.0f + sv;
        const float lr = (float)(li + HALO);
        const float lc = (float)(lj + HALO);
        const int ra0 = (int)floorf(lr - tt); const float fya = (lr - tt) - (float)ra0;
        const int rb0 = (int)floorf(lr + tt); const float fyb = (lr + tt) - (float)rb0;
        const int ca0 = (int)floorf(lc - tt); const float fxa = (lc - tt) - (float)ca0;
        const int cb0 = (int)floorf(lc + tt); const float fxb = (lc + tt) - (float)cb0;
        const int rc = li + HALO, cc = lj + HALO;
        const __half2 fxa2 = __float2half2_rn(fxa);
        const __half2 fxb2 = __float2half2_rn(fxb);
        const __half2 fya2 = __float2half2_rn(fya);
        const __half2 fyb2 = __float2half2_rn(fyb);

        __half2 A0[4], C0[4], B0[4], A1[4], C1[4], B1[4];

#define LOADCOLS(ro, Av, Cv, Bv) do {                                   \
        uint4 v0 = smem[(ro) + ca0]; uint4 v1 = smem[(ro) + ca0 + 1];   \
        uint4 vc = smem[(ro) + cc];                                     \
        uint4 v3 = smem[(ro) + cb0]; uint4 v4 = smem[(ro) + cb0 + 1];   \
        const uint32_t* p0 = (const uint32_t*)&v0;                      \
        const uint32_t* p1 = (const uint32_t*)&v1;                      \
        const uint32_t* pc = (const uint32_t*)&vc;                      \
        const uint32_t* p3 = (const uint32_t*)&v3;                      \
        const uint32_t* p4 = (const uint32_t*)&v4;                      \
        _Pragma("unroll")                                               \
        for (int pp = 0; pp < 4; ++pp) {                                \
            Av[pp] = lerp2(u2h(p0[pp]), u2h(p1[pp]), fxa2);             \
            Cv[pp] = u2h(pc[pp]);                                       \
            Bv[pp] = lerp2(u2h(p3[pp]), u2h(p4[pp]), fxb2);             \
        } } while (0)

        __half2 acc[4];
        // ky = 0 : rows ra0, ra0+1 lerped by fya
        LOADCOLS(ra0 * RD, A0, C0, B0);
        LOADCOLS((ra0 + 1) * RD, A1, C1, B1);
        #pragma unroll
        for (int pp = 0; pp < 4; ++pp) {
            __half2 SA = lerp2(A0[pp], A1[pp], fya2);
            __half2 SC = lerp2(C0[pp], C1[pp], fya2);
            __half2 SB = lerp2(B0[pp], B1[pp], fya2);
            acc[pp] = __hmul2(d2[pp][0], SA);
            acc[pp] = __hfma2(d2[pp][1], SC, acc[pp]);
            acc[pp] = __hfma2(d2[pp][2], SB, acc[pp]);
        }
        // ky = 1 : exact center row
        LOADCOLS(rc * RD, A0, C0, B0);
        #pragma unroll
        for (int pp = 0; pp < 4; ++pp) {
            acc[pp] = __hfma2(d2[pp][3], A0[pp], acc[pp]);
            acc[pp] = __hfma2(d2[pp][4], C0[pp], acc[pp]);
            acc[pp] = __hfma2(d2[pp][5], B0[pp], acc[pp]);
        }
        // ky = 2 : rows rb0, rb0+1 lerped by fyb
        LOADCOLS(rb0 * RD, A0, C0, B0);
        LOADCOLS((rb0 + 1) * RD, A1, C1, B1);
        #pragma unroll
        for (int pp = 0; pp < 4; ++pp) {
            __half2 SA = lerp2(A0[pp], A1[pp], fyb2);
            __half2 SC = lerp2(C0[pp], C1[pp], fyb2);
            __half2 SB = lerp2(B0[pp], B1[pp], fyb2);
            acc[pp] = __hfma2(d2[pp][6], SA, acc[pp]);
            acc[pp] = __hfma2(d2[pp][7], SC, acc[pp]);
            acc[pp] = __hfma2(d2[pp][8], SB, acc[pp]);
        }
#undef LOADCOLS

        const size_t ob = ((size_t)n * 64 + c0) * HW_ + gi * W_ + gj;
        #pragma unroll
        for (int pp = 0; pp < 4; ++pp) {
            out[ob + (size_t)(2 * pp) * HW_]     = __low2float(acc[pp]);
            out[ob + (size_t)(2 * pp + 1) * HW_] = __high2float(acc[pp]);
        }
    }
}

extern "C" void kernel_launch(void* const* d_in, const int* in_sizes, int n_in,
                              void* d_out, int out_size, void* d_ws, size_t ws_size,
                              hipStream_t stream) {
    const float* x    = (const float*)d_in[0];
    const float* pw   = (const float*)d_in[1];
    const float* offw = (const float*)d_in[2];
    const float* offb = (const float*)d_in[3];
    const float* dwp  = (const float*)d_in[4];

    uint32_t* ypackI = (uint32_t*)d_ws;                                 // 64 MiB
    float* sbuf = (float*)((char*)d_ws + (size_t)NIMG * 8 * HW_ * 16);  // 2 MiB
    float* out  = (float*)d_out;

    hipLaunchKernelGGL(pw_off_kernel, dim3(2048), dim3(256), 0, stream,
                       x, pw, offw, offb, ypackI, sbuf);
    hipLaunchKernelGGL(deform_kernel, dim3(8, 8, NIMG * 8), dim3(256), 0, stream,
                       (const uint4*)ypackI, sbuf, dwp, out);
}

// Round 4
// 292.106 us; speedup vs baseline: 1.2856x; 1.0159x over previous
//
#include <hip/hip_runtime.h>
#include <hip/hip_fp16.h>
#include <stdint.h>

#define H_   256
#define W_   256
#define HW_  65536
#define NIMG 8

#define TI   32
#define TJ   32
#define HALO 10
#define RD   52   // TI + 2*HALO

typedef _Float16 half8_t __attribute__((ext_vector_type(8)));
typedef __fp16   fp16x2  __attribute__((ext_vector_type(2)));
typedef float    float4_t __attribute__((ext_vector_type(4)));

__device__ __forceinline__ uint32_t pk2(float a, float b) {
    fp16x2 h = __builtin_amdgcn_cvt_pkrtz(a, b);
    union { fp16x2 h; uint32_t u; } v; v.h = h; return v.u;
}
__device__ __forceinline__ __half2 u2h(uint32_t u) {
    union { uint32_t u; __half2 h; } v; v.u = u; return v.h;
}
__device__ __forceinline__ __half2 lerp2(__half2 p, __half2 q, __half2 f) {
    return __hfma2(f, __hsub2(q, p), p);
}

// ---------------- Kernel A: pointwise conv via MFMA f16, direct global loads ----------------
// No LDS, no barrier: B-fragments (8 consecutive channels x same pixel) loaded straight
// from x with per-channel coalesced dword loads. 4 independent j-iterations give MLP.
// ypackI layout (u32): [(n*8 + pg)*HW + hw]*4 + ppl ; channel c = pg*8 + ppl*2 (+1 hi half)
__global__ __launch_bounds__(256) void pw_off_kernel(
    const float* __restrict__ x, const float* __restrict__ pw,
    const float* __restrict__ offw, const float* __restrict__ offb,
    uint32_t* __restrict__ ypackI, float* __restrict__ sbuf)
{
    const int t    = threadIdx.x;
    const int blk  = blockIdx.x;          // 2048 blocks, 256 px each
    const int n    = blk >> 8;
    const int hw0  = (blk & 255) << 8;
    const int lane = t & 63;
    const int l15  = lane & 15;
    const int q    = lane >> 4;
    const int wv   = t >> 6;

    // ---- A fragments: af[mt][kt], A[m][k]: m = l15, k = q*8 + j ----
    half8_t af[4][2];
    #pragma unroll
    for (int mt = 0; mt < 4; ++mt) {
        #pragma unroll
        for (int kt = 0; kt < 2; ++kt) {
            const float* wr = pw + (mt * 16 + l15) * 64 + kt * 32 + q * 8;
            float4 w0 = *(const float4*)wr;
            float4 w1 = *(const float4*)(wr + 4);
            union { uint32_t u[4]; half8_t h; } v;
            v.u[0] = pk2(w0.x, w0.y); v.u[1] = pk2(w0.z, w0.w);
            v.u[2] = pk2(w1.x, w1.y); v.u[3] = pk2(w1.z, w1.w);
            af[mt][kt] = v.h;
        }
    }
    float4_t ow4[4];
    #pragma unroll
    for (int mt = 0; mt < 4; ++mt)
        ow4[mt] = *(const float4_t*)(offw + mt * 16 + q * 4);
    const float bias = offb[0];

    #pragma unroll
    for (int j = 0; j < 4; ++j) {
        const int pix = (wv * 4 + j) * 16 + l15;
        const int hw  = hw0 + pix;
        const float* xp = x + (size_t)n * 64 * HW_ + hw;

        // B fragments: B[k][nn]: nn = l15 (pixel), k = q*8 + jj  -> 8 channel dword loads
        half8_t bf[2];
        #pragma unroll
        for (int kt = 0; kt < 2; ++kt) {
            const float* xk = xp + (size_t)(kt * 32 + q * 8) * HW_;
            float v0 = xk[0 * (size_t)HW_];
            float v1 = xk[1 * (size_t)HW_];
            float v2 = xk[2 * (size_t)HW_];
            float v3 = xk[3 * (size_t)HW_];
            float v4 = xk[4 * (size_t)HW_];
            float v5 = xk[5 * (size_t)HW_];
            float v6 = xk[6 * (size_t)HW_];
            float v7 = xk[7 * (size_t)HW_];
            union { uint32_t u[4]; half8_t h; } vv;
            vv.u[0] = pk2(v0, v1); vv.u[1] = pk2(v2, v3);
            vv.u[2] = pk2(v4, v5); vv.u[3] = pk2(v6, v7);
            bf[kt] = vv.h;
        }

        float4_t acc[4] = {{0,0,0,0},{0,0,0,0},{0,0,0,0},{0,0,0,0}};
        #pragma unroll
        for (int kt = 0; kt < 2; ++kt) {
            #pragma unroll
            for (int mt = 0; mt < 4; ++mt)
                acc[mt] = __builtin_amdgcn_mfma_f32_16x16x32_f16(af[mt][kt], bf[kt], acc[mt], 0, 0, 0);
        }

        // ---- offset scalar: s = clip(y . ow + b) — reduce over the 4 quads ----
        float sp = 0.f;
        #pragma unroll
        for (int mt = 0; mt < 4; ++mt)
            sp += acc[mt][0] * ow4[mt][0] + acc[mt][1] * ow4[mt][1]
                + acc[mt][2] * ow4[mt][2] + acc[mt][3] * ow4[mt][3];
        sp += __shfl_xor(sp, 16, 64);
        sp += __shfl_xor(sp, 32, 64);
        float sv = fminf(fmaxf(sp + bias, 0.f), 8.f);
        if (q == 0) sbuf[(size_t)n * HW_ + hw] = sv;

        // ---- pack y to f16 pairs, store interleaved-by-4-planes ----
        #pragma unroll
        for (int mt = 0; mt < 4; ++mt) {
            uint2 st;
            st.x = pk2(acc[mt][0], acc[mt][1]);
            st.y = pk2(acc[mt][2], acc[mt][3]);
            const int pg = mt * 2 + (q >> 1);
            size_t ad = (((size_t)(n * 8 + pg)) * HW_ + hw) * 4 + (q & 1) * 2;
            *(uint2*)&ypackI[ad] = st;
        }
    }
}

// ---------------- Kernel B: deformable depthwise 3x3, separable bilinear ----------------
// block = 32x32 pixel tile x 1 plane-group (4 half2-planes = 8 channels).
// Staged region interleaved: one ds_read_b128 per sample point serves 8 channels.
__global__ __launch_bounds__(256) void deform_kernel(
    const uint4* __restrict__ ypackI, const float* __restrict__ sbuf,
    const float* __restrict__ dwp, float* __restrict__ out)
{
    __shared__ uint4 smem[RD * RD];   // 43.3 KB

    const int t  = threadIdx.x;
    const int tj = blockIdx.x;   // 0..7
    const int ti = blockIdx.y;   // 0..7
    const int z  = blockIdx.z;   // n*8 + pg
    const int n  = z >> 3;
    const int pg = z & 7;
    const int i0 = ti * TI, j0 = tj * TJ;

    // stage zero-padded interleaved region
    const size_t ybase = (size_t)z * HW_;
    for (int idx = t; idx < RD * RD; idx += 256) {
        int r  = idx / RD;
        int c  = idx - r * RD;
        int gr = i0 - HALO + r;
        int gc = j0 - HALO + c;
        bool ok = (gr >= 0) & (gr < H_) & (gc >= 0) & (gc < W_);
        uint4 v = {0u, 0u, 0u, 0u};
        if (ok) v = ypackI[ybase + gr * W_ + gc];
        smem[idx] = v;
    }

    // depthwise weights (uniform scalar loads), packed per channel-pair
    const int c0 = pg * 8;
    __half2 d2[4][9];
    #pragma unroll
    for (int pp = 0; pp < 4; ++pp) {
        #pragma unroll
        for (int k = 0; k < 9; ++k)
            d2[pp][k] = __floats2half2_rn(dwp[(c0 + 2 * pp) * 9 + k],
                                          dwp[(c0 + 2 * pp + 1) * 9 + k]);
    }
    __syncthreads();

    #pragma unroll
    for (int qq = 0; qq < 4; ++qq) {
        const int li = (t >> 5) + qq * 8;
        const int lj = t & 31;
        const int gi = i0 + li, gj = j0 + lj;
        const float sv = sbuf[(size_t)n * HW_ + gi * W_ + gj];
        const float tt = 1.0f + sv;
        const float lr = (float)(li + HALO);
        const float lc = (float)(lj + HALO);
        const int ra0 = (int)floorf(lr - tt); const float fya = (lr - tt) - (float)ra0;
        const int rb0 = (int)floorf(lr + tt); const float fyb = (lr + tt) - (float)rb0;
        const int ca0 = (int)floorf(lc - tt); const float fxa = (lc - tt) - (float)ca0;
        const int cb0 = (int)floorf(lc + tt); const float fxb = (lc + tt) - (float)cb0;
        const int rc = li + HALO, cc = lj + HALO;
        const __half2 fxa2 = __float2half2_rn(fxa);
        const __half2 fxb2 = __float2half2_rn(fxb);
        const __half2 fya2 = __float2half2_rn(fya);
        const __half2 fyb2 = __float2half2_rn(fyb);

        __half2 A0[4], C0[4], B0[4], A1[4], C1[4], B1[4];

#define LOADCOLS(ro, Av, Cv, Bv) do {                                   \
        uint4 v0 = smem[(ro) + ca0]; uint4 v1 = smem[(ro) + ca0 + 1];   \
        uint4 vc = smem[(ro) + cc];                                     \
        uint4 v3 = smem[(ro) + cb0]; uint4 v4 = smem[(ro) + cb0 + 1];   \
        const uint32_t* p0 = (const uint32_t*)&v0;                      \
        const uint32_t* p1 = (const uint32_t*)&v1;                      \
        const uint32_t* pc = (const uint32_t*)&vc;                      \
        const uint32_t* p3 = (const uint32_t*)&v3;                      \
        const uint32_t* p4 = (const uint32_t*)&v4;                      \
        _Pragma("unroll")                                               \
        for (int pp = 0; pp < 4; ++pp) {                                \
            Av[pp] = lerp2(u2h(p0[pp]), u2h(p1[pp]), fxa2);             \
            Cv[pp] = u2h(pc[pp]);                                       \
            Bv[pp] = lerp2(u2h(p3[pp]), u2h(p4[pp]), fxb2);             \
        } } while (0)

        __half2 acc[4];
        // ky = 0 : rows ra0, ra0+1 lerped by fya
        LOADCOLS(ra0 * RD, A0, C0, B0);
        LOADCOLS((ra0 + 1) * RD, A1, C1, B1);
        #pragma unroll
        for (int pp = 0; pp < 4; ++pp) {
            __half2 SA = lerp2(A0[pp], A1[pp], fya2);
            __half2 SC = lerp2(C0[pp], C1[pp], fya2);
            __half2 SB = lerp2(B0[pp], B1[pp], fya2);
            acc[pp] = __hmul2(d2[pp][0], SA);
            acc[pp] = __hfma2(d2[pp][1], SC, acc[pp]);
            acc[pp] = __hfma2(d2[pp][2], SB, acc[pp]);
        }
        // ky = 1 : exact center row
        LOADCOLS(rc * RD, A0, C0, B0);
        #pragma unroll
        for (int pp = 0; pp < 4; ++pp) {
            acc[pp] = __hfma2(d2[pp][3], A0[pp], acc[pp]);
            acc[pp] = __hfma2(d2[pp][4], C0[pp], acc[pp]);
            acc[pp] = __hfma2(d2[pp][5], B0[pp], acc[pp]);
        }
        // ky = 2 : rows rb0, rb0+1 lerped by fyb
        LOADCOLS(rb0 * RD, A0, C0, B0);
        LOADCOLS((rb0 + 1) * RD, A1, C1, B1);
        #pragma unroll
        for (int pp = 0; pp < 4; ++pp) {
            __half2 SA = lerp2(A0[pp], A1[pp], fyb2);
            __half2 SC = lerp2(C0[pp], C1[pp], fyb2);
            __half2 SB = lerp2(B0[pp], B1[pp], fyb2);
            acc[pp] = __hfma2(d2[pp][6], SA, acc[pp]);
            acc[pp] = __hfma2(d2[pp][7], SC, acc[pp]);
            acc[pp] = __hfma2(d2[pp][8], SB, acc[pp]);
        }
#undef LOADCOLS

        const size_t ob = ((size_t)n * 64 + c0) * HW_ + gi * W_ + gj;
        #pragma unroll
        for (int pp = 0; pp < 4; ++pp) {
            out[ob + (size_t)(2 * pp) * HW_]     = __low2float(acc[pp]);
            out[ob + (size_t)(2 * pp + 1) * HW_] = __high2float(acc[pp]);
        }
    }
}

extern "C" void kernel_launch(void* const* d_in, const int* in_sizes, int n_in,
                              void* d_out, int out_size, void* d_ws, size_t ws_size,
                              hipStream_t stream) {
    const float* x    = (const float*)d_in[0];
    const float* pw   = (const float*)d_in[1];
    const float* offw = (const float*)d_in[2];
    const float* offb = (const float*)d_in[3];
    const float* dwp  = (const float*)d_in[4];

    uint32_t* ypackI = (uint32_t*)d_ws;                                 // 64 MiB
    float* sbuf = (float*)((char*)d_ws + (size_t)NIMG * 8 * HW_ * 16);  // 2 MiB
    float* out  = (float*)d_out;

    hipLaunchKernelGGL(pw_off_kernel, dim3(2048), dim3(256), 0, stream,
                       x, pw, offw, offb, ypackI, sbuf);
    hipLaunchKernelGGL(deform_kernel, dim3(8, 8, NIMG * 8), dim3(256), 0, stream,
                       (const uint4*)ypackI, sbuf, dwp, out);
}